// Round 1
// baseline (297.048 us; speedup 1.0000x reference)
//
#include <hip/hip_runtime.h>

typedef __bf16 bf16;
typedef bf16 bf16x8 __attribute__((ext_vector_type(8)));
typedef bf16 bf16x4 __attribute__((ext_vector_type(4)));
typedef float f32x4 __attribute__((ext_vector_type(4)));

#define BB 8192   // batch
#define NN 2048   // nodes

// ---------------------------------------------------------------------------
// async global->LDS, 16B per lane. LDS dest must be wave-uniform base;
// HW scatters lane i at base + i*16.
__device__ __forceinline__ void async16(const void* g, void* l) {
    __builtin_amdgcn_global_load_lds(
        (__attribute__((address_space(1))) void*)(void*)g,
        (__attribute__((address_space(3))) void*)l,
        16, 0, 0);
}

// ---------------------------------------------------------------------------
// K1: per x-row gather-conv.  V[bb][g] = relu(cb + sum_w cw[0][w]*x[bb,adj[g,w]]
//                                                 + cw[1][w]*label[bb,adj[g,w]])
// One block per bb. Stage x-row & label-row interleaved (float2) in LDS,
// gather with ds_read_b64, coalesced bf16 writes along g.
__global__ __launch_bounds__(256) void conv_gather(
    const float* __restrict__ x, const float* __restrict__ label,
    const int* __restrict__ adj, const float* __restrict__ cw,
    const float* __restrict__ cb, bf16* __restrict__ V) {
    __shared__ float2 sxl[NN];   // 16 KB: (x, label) pairs
    const int bb = blockIdx.x;
    const int t  = threadIdx.x;

    const float4* xr = (const float4*)(x     + (size_t)bb * NN);
    const float4* lr = (const float4*)(label + (size_t)bb * NN);
#pragma unroll
    for (int q = 0; q < 2; ++q) {
        int i = q * 256 + t;             // float4 index, 512 total
        float4 xv = xr[i];
        float4 lv = lr[i];
        sxl[i*4+0] = make_float2(xv.x, lv.x);
        sxl[i*4+1] = make_float2(xv.y, lv.y);
        sxl[i*4+2] = make_float2(xv.z, lv.z);
        sxl[i*4+3] = make_float2(xv.w, lv.w);
    }
    const float w0 = cw[0], w1 = cw[1], w2 = cw[2], w3 = cw[3];
    const float w4 = cw[4], w5 = cw[5], w6 = cw[6], w7 = cw[7];
    const float bias = cb[0];
    __syncthreads();

    const int4* adj4 = (const int4*)adj;   // adj is (2048,4) int32, 16B rows
    bf16* vrow = V + (size_t)bb * NN;
#pragma unroll
    for (int it = 0; it < 8; ++it) {
        int g = it * 256 + t;
        int4 a = adj4[g];
        float2 p0 = sxl[a.x];
        float2 p1 = sxl[a.y];
        float2 p2 = sxl[a.z];
        float2 p3 = sxl[a.w];
        float v = bias
                + w0 * p0.x + w1 * p1.x + w2 * p2.x + w3 * p3.x
                + w4 * p0.y + w5 * p1.y + w6 * p2.y + w7 * p3.y;
        v = fmaxf(v, 0.0f);
        vrow[g] = (bf16)v;
    }
}

// ---------------------------------------------------------------------------
// Kw: lin_w f32 -> bf16 (row-major copy), 1 float4 per thread.
__global__ __launch_bounds__(256) void cvtw(const float* __restrict__ W,
                                            bf16* __restrict__ Wb) {
    size_t i = (size_t)blockIdx.x * 256 + threadIdx.x;   // float4 index
    float4 v = ((const float4*)W)[i];
    bf16x4 o;
    o.x = (bf16)v.x; o.y = (bf16)v.y; o.z = (bf16)v.z; o.w = (bf16)v.w;
    ((bf16x4*)Wb)[i] = o;
}

// ---------------------------------------------------------------------------
// K2: transpose V (8192 x 2048, bf16) -> Y2 (2048 x 8192, bf16).
// Flat Y2 row-major == y2 (the GEMM A matrix, 8192 x 2048) by the reshape algebra.
__global__ __launch_bounds__(256) void transp(const unsigned short* __restrict__ V,
                                              unsigned short* __restrict__ Y) {
    __shared__ unsigned short tile[64][65];   // +1 pad
    const int g0 = blockIdx.x * 64;   // V col / Y row
    const int p0 = blockIdx.y * 64;   // V row / Y col
    const int tx = threadIdx.x & 63;
    const int ty = threadIdx.x >> 6;
#pragma unroll
    for (int q = 0; q < 16; ++q) {
        int r = q * 4 + ty;
        tile[r][tx] = V[(size_t)(p0 + r) * NN + g0 + tx];
    }
    __syncthreads();
#pragma unroll
    for (int q = 0; q < 16; ++q) {
        int r = q * 4 + ty;
        Y[(size_t)(g0 + r) * BB + p0 + tx] = tile[tx][r];
    }
}

// ---------------------------------------------------------------------------
// K3: out(8192x2048) = A(8192x2048,bf16) * W(2048x2048,bf16)^T + bias, fp32 out.
// m97 structure: 128x128 tile, BK=32, 4 waves each 64x64 via 4x4 mfma 16x16x32,
// global_load_lds width 16, single LDS buffer, 2 barriers per K-iter.
__global__ __launch_bounds__(256) void gemm_bt(
    const bf16* __restrict__ A, const bf16* __restrict__ W,
    const float* __restrict__ bias, float* __restrict__ out) {
    __shared__ __attribute__((aligned(16))) bf16 sA[128 * 32];
    __shared__ __attribute__((aligned(16))) bf16 sB[128 * 32];

    const int t    = threadIdx.x;
    const int lane = t & 63;
    const int wv   = t >> 6;        // wave 0..3
    const int wm   = wv & 1;        // M half of the 128x128 tile
    const int wn   = wv >> 1;       // N half
    const int m0   = blockIdx.x * 128;
    const int n0   = blockIdx.y * 128;

    f32x4 acc[4][4] = {};

    // staging: thread t covers tile row r=(t>>2) (+64 on 2nd inst), 16B chunk (t&3)
    const int r  = t >> 2;
    const int c8 = (t & 3) * 8;
    const bf16* gA0 = A + (size_t)(m0 + r)      * 2048 + c8;
    const bf16* gA1 = A + (size_t)(m0 + r + 64) * 2048 + c8;
    const bf16* gB0 = W + (size_t)(n0 + r)      * 2048 + c8;
    const bf16* gB1 = W + (size_t)(n0 + r + 64) * 2048 + c8;
    // wave-uniform LDS bases: wave wv covers 16 rows per instruction
    bf16* lA0 = sA + (wv * 16)      * 32;
    bf16* lA1 = sA + (64 + wv * 16) * 32;
    bf16* lB0 = sB + (wv * 16)      * 32;
    bf16* lB1 = sB + (64 + wv * 16) * 32;

    // fragment read bases: lane holds A[m=lane&15][k=quad*8..+8]
    const int quad = lane >> 4;
    const int l16  = lane & 15;
    const bf16* fA = sA + (wm * 64 + l16) * 32 + quad * 8;
    const bf16* fB = sB + (wn * 64 + l16) * 32 + quad * 8;

    for (int k0 = 0; k0 < 2048; k0 += 32) {
        async16(gA0 + k0, lA0);
        async16(gA1 + k0, lA1);
        async16(gB0 + k0, lB0);
        async16(gB1 + k0, lB1);
        __syncthreads();            // drains vmcnt -> staging visible

        bf16x8 af[4], bfr[4];
#pragma unroll
        for (int i = 0; i < 4; ++i) af[i]  = *(const bf16x8*)(fA + i * 16 * 32);
#pragma unroll
        for (int j = 0; j < 4; ++j) bfr[j] = *(const bf16x8*)(fB + j * 16 * 32);
#pragma unroll
        for (int i = 0; i < 4; ++i)
#pragma unroll
            for (int j = 0; j < 4; ++j)
                acc[i][j] = __builtin_amdgcn_mfma_f32_16x16x32_bf16(
                    af[i], bfr[j], acc[i][j], 0, 0, 0);
        __syncthreads();            // protect sA/sB before next staging
    }

    // epilogue: C/D layout col = lane&15, row = quad*4 + rr
#pragma unroll
    for (int j = 0; j < 4; ++j) {
        int col = n0 + wn * 64 + j * 16 + l16;
        float bcol = bias[col];
#pragma unroll
        for (int i = 0; i < 4; ++i) {
            int rowb = m0 + wm * 64 + i * 16 + quad * 4;
#pragma unroll
            for (int rr = 0; rr < 4; ++rr) {
                out[(size_t)(rowb + rr) * 2048 + col] = acc[i][j][rr] + bcol;
            }
        }
    }
}

// ---------------------------------------------------------------------------
extern "C" void kernel_launch(void* const* d_in, const int* in_sizes, int n_in,
                              void* d_out, int out_size, void* d_ws, size_t ws_size,
                              hipStream_t stream) {
    (void)in_sizes; (void)n_in; (void)out_size; (void)ws_size;
    const float* x     = (const float*)d_in[0];
    const float* label = (const float*)d_in[1];
    const int*   adj   = (const int*)d_in[2];
    const float* cw    = (const float*)d_in[3];
    const float* cb    = (const float*)d_in[4];
    const float* lw    = (const float*)d_in[5];
    const float* lb    = (const float*)d_in[6];
    float* out = (float*)d_out;

    // scratch layout:
    //   V  (8192x2048 bf16, 32MB) lives in d_out's first half (overwritten by GEMM)
    //   Y2 (transposed, == A matrix flat, 32MB) at ws+0
    //   Wb (lin_w bf16, 8MB) at ws+32MB    -> needs ws_size >= 40MB
    bf16* V  = (bf16*)d_out;
    bf16* Y2 = (bf16*)d_ws;
    bf16* Wb = (bf16*)((char*)d_ws + (size_t)2048 * 8192 * 2);

    conv_gather<<<BB, 256, 0, stream>>>(x, label, adj, cw, cb, V);
    cvtw<<<4096, 256, 0, stream>>>(lw, Wb);
    transp<<<dim3(32, 128), 256, 0, stream>>>((const unsigned short*)V,
                                              (unsigned short*)Y2);
    gemm_bt<<<dim3(64, 16), 256, 0, stream>>>(Y2, Wb, lb, out);
}